// Round 5
// baseline (104.540 us; speedup 1.0000x reference)
//
#include <hip/hip_runtime.h>
#include <math.h>

// Problem constants (match reference)
#define Lp 1024
#define Bp 64
#define Tt 128          // tile rows
#define NTILE 8         // Lp / Tt
#define NPAIR 36        // NTILE*(NTILE+1)/2 triangular tile pairs
#define NBLK (Bp * NPAIR)   // 2304 blocks

typedef float v4f __attribute__((ext_vector_type(4)));
static __device__ __forceinline__ v4f splat4(float s) {
    v4f r; r.x = s; r.y = s; r.z = s; r.w = s; return r;
}

// One block = one (batch, triangular tile-pair), 256 threads.
// Lane map: jsl = (t&7)*4 -> 4 adjacent j columns (float4/pk math),
//           rg  = t>>3    -> 4 i-rows [rg*4, rg*4+4); wave w owns rows [32w,32w+32).
// jj loop covers 32-column j groups; per-group validity flags allow
// wave-uniform skipping of fully-masked groups (mask rows contribute 0).
// One sqrt per pair: (dy-dx)^2 = d2x + d2y - 2*sqrt(d2x*d2y), diff-form d2 >= 0.
// Final reduction fused: last block (device atomic counter) reduces partials.
__global__ __launch_bounds__(256) void drmsd_fused(
    const float* __restrict__ x, const float* __restrict__ y,
    float* __restrict__ partials, unsigned* __restrict__ counter,
    float* __restrict__ out)
{
    __shared__ __align__(16) float xsx[2][Tt], xsy[2][Tt], xsz[2][Tt];
    __shared__ __align__(16) float ysx[2][Tt], ysy[2][Tt], ysz[2][Tt];
    __shared__ __align__(16) float ms[2][Tt];
    __shared__ unsigned vflags[2];   // [0]=i-tile row-group bits, [1]=j-tile
    __shared__ float red[4];
    __shared__ int   lastFlag;
    __shared__ float sums[256];

    const int b = blockIdx.x;      // batch
    const int p = blockIdx.y;      // triangular pair index 0..35

    // decode p -> (ti, tj), ti <= tj
    int ti = 0, base = 0;
    while (p >= base + (NTILE - ti)) { base += (NTILE - ti); ++ti; }
    const int tj = ti + (p - base);

    const int t = threadIdx.x;
    if (t < 2) vflags[t] = 0u;
    __syncthreads();

    // ---- stage: threads 0-127 -> i-tile (slot 0), 128-255 -> j-tile (slot 1)
    {
        const int r     = t & (Tt - 1);
        const int which = t >> 7;
        const int tile  = which ? tj : ti;
        const int row   = tile * Tt + r;
        const float* px = x + (size_t)row * (Bp * 3) + (size_t)b * 3;
        const float* py = y + (size_t)row * (Bp * 3) + (size_t)b * 3;
        const float x0 = px[0], x1 = px[1], x2 = px[2];
        const float y0 = py[0], y1 = py[1], y2 = py[2];
        xsx[which][r] = x0; xsy[which][r] = x1; xsz[which][r] = x2;
        ysx[which][r] = y0; ysy[which][r] = y1; ysz[which][r] = y2;
        const bool valid = ((y0 + y1 + y2) != 0.0f);
        ms[which][r] = valid ? 1.0f : 0.0f;
        if (valid) atomicOr(&vflags[which], 1u << (r >> 5));
    }
    __syncthreads();

    const unsigned imask = vflags[0];
    const unsigned jmask = vflags[1];

    const int jsl = (t & 7) << 2;    // j column offset within 32-group: 0,4,..,28
    const int rg  = t >> 3;          // 0..31
    const int i0  = rg << 2;         // i-rows i0..i0+3
    const int wv  = t >> 6;          // wave id == i-row-group bit

    float total = 0.0f;

    if (imask & (1u << wv)) {
        // i-row registers (4 rows per component)
        const float4 v_xx = *(const float4*)&xsx[0][i0];
        const float4 v_xy = *(const float4*)&xsy[0][i0];
        const float4 v_xz = *(const float4*)&xsz[0][i0];
        const float4 v_yx = *(const float4*)&ysx[0][i0];
        const float4 v_yy = *(const float4*)&ysy[0][i0];
        const float4 v_yz = *(const float4*)&ysz[0][i0];
        const float4 v_mi = *(const float4*)&ms[0][i0];
        const float xix[4] = { v_xx.x, v_xx.y, v_xx.z, v_xx.w };
        const float xiy[4] = { v_xy.x, v_xy.y, v_xy.z, v_xy.w };
        const float xiz[4] = { v_xz.x, v_xz.y, v_xz.z, v_xz.w };
        const float yix[4] = { v_yx.x, v_yx.y, v_yx.z, v_yx.w };
        const float yiy[4] = { v_yy.x, v_yy.y, v_yy.z, v_yy.w };
        const float yiz[4] = { v_yz.x, v_yz.y, v_yz.z, v_yz.w };
        const float mir[4] = { v_mi.x, v_mi.y, v_mi.z, v_mi.w };

        v4f acc[4];
#pragma unroll
        for (int r = 0; r < 4; ++r) acc[r] = splat4(0.0f);

        const v4f neg2 = splat4(-2.0f);

#pragma unroll
        for (int jj = 0; jj < 4; ++jj) {
            if (!(jmask & (1u << jj))) continue;   // whole 32-col group masked
            const int j0 = jj * 32 + jsl;
            const v4f xjx = *(const v4f*)&xsx[1][j0];
            const v4f xjy = *(const v4f*)&xsy[1][j0];
            const v4f xjz = *(const v4f*)&xsz[1][j0];
            const v4f yjx = *(const v4f*)&ysx[1][j0];
            const v4f yjy = *(const v4f*)&ysy[1][j0];
            const v4f yjz = *(const v4f*)&ysz[1][j0];
            const v4f mj  = *(const v4f*)&ms[1][j0];
#pragma unroll
            for (int r = 0; r < 4; ++r) {
                const v4f ax = splat4(xix[r]) - xjx;
                const v4f ay = splat4(xiy[r]) - xjy;
                const v4f az = splat4(xiz[r]) - xjz;
                const v4f d2x = ax * ax + ay * ay + az * az;   // pk_fma chain
                const v4f bx = splat4(yix[r]) - yjx;
                const v4f by = splat4(yiy[r]) - yjy;
                const v4f bz = splat4(yiz[r]) - yjz;
                const v4f d2y = bx * bx + by * by + bz * bz;
                const v4f pr = d2x * d2y;                      // exactly >= 0
                v4f sq;
                sq.x = __builtin_amdgcn_sqrtf(pr.x);
                sq.y = __builtin_amdgcn_sqrtf(pr.y);
                sq.z = __builtin_amdgcn_sqrtf(pr.z);
                sq.w = __builtin_amdgcn_sqrtf(pr.w);
                const v4f u = (d2x + d2y) + neg2 * sq;
                acc[r] = mj * u + acc[r];                      // col mask
            }
        }
#pragma unroll
        for (int r = 0; r < 4; ++r)
            total = fmaf(acc[r].x + acc[r].y + acc[r].z + acc[r].w, mir[r], total);
    }

    // ---- block reduction ----
#pragma unroll
    for (int off = 32; off > 0; off >>= 1)
        total += __shfl_down(total, off, 64);
    if ((t & 63) == 0) red[wv] = total;
    __syncthreads();
    if (t == 0) {
        float s = red[0] + red[1] + red[2] + red[3];
        if (ti != tj) s *= 2.0f;   // off-diagonal pair counted for both orders
        partials[(size_t)p * Bp + b] = s;
        __threadfence();           // make partial visible before signaling
        const unsigned old = atomicAdd(counter, 1u);
        lastFlag = (old == NBLK - 1) ? 1 : 0;
    }
    __syncthreads();

    // ---- last block performs the final reduction ----
    if (lastFlag) {
        __threadfence();           // acquire: see all partials
        const int lane = t & 63;
        const int q    = t >> 6;   // wave q handles 9 p's
        float s = 0.0f;
#pragma unroll
        for (int k = 0; k < 9; ++k) {
            const int pidx = q * 9 + k;
            s += partials[(size_t)pidx * Bp + lane];
        }
        sums[t] = s;
        __syncthreads();
        if (t < 64) {
            float v = sums[t] + sums[t + 64] + sums[t + 128] + sums[t + 192];
            float pb = sqrtf(v);
#pragma unroll
            for (int off = 32; off > 0; off >>= 1)
                pb += __shfl_down(pb, off, 64);
            if (t == 0) {
                const double denom = sqrt((double)Lp * (double)Lp / 2.0 - (double)Lp);
                out[0] = (float)((double)pb / denom / (double)Bp);
            }
        }
    }
}

extern "C" void kernel_launch(void* const* d_in, const int* in_sizes, int n_in,
                              void* d_out, int out_size, void* d_ws, size_t ws_size,
                              hipStream_t stream) {
    const float* x = (const float*)d_in[0];
    const float* y = (const float*)d_in[1];
    float* out      = (float*)d_out;
    float* partials = (float*)d_ws;                       // NPAIR*Bp floats = 9216 B
    unsigned* counter = (unsigned*)((char*)d_ws + 9216);  // 4 B, zeroed each launch

    hipMemsetAsync(counter, 0, sizeof(unsigned), stream);
    dim3 grid(Bp, NPAIR);
    drmsd_fused<<<grid, 256, 0, stream>>>(x, y, partials, counter, out);
}

// Round 6
// 103.604 us; speedup vs baseline: 1.0090x; 1.0090x over previous
//
#include <hip/hip_runtime.h>
#include <math.h>

// Problem constants (match reference)
#define Lp 1024
#define Bp 64
#define Tt 128          // tile rows
#define NTILE 8         // Lp / Tt
#define NPAIR 36        // NTILE*(NTILE+1)/2 triangular tile pairs
#define NBLK (Bp * NPAIR)   // 2304 blocks

typedef float v4f __attribute__((ext_vector_type(4)));
static __device__ __forceinline__ v4f splat4(float s) {
    v4f r; r.x = s; r.y = s; r.z = s; r.w = s; return r;
}

// One block = one (batch, triangular tile-pair), 256 threads.
// Lane map: jsl = (t&7)*4 -> 4 adjacent j columns (ds_read_b128 + pk-f32 math),
//           rg  = t>>3 in 0..31 -> i-rows [rg*4, rg*4+4).
// Coverage/thread: 4 rows x 16 cols = 64 pairs. NO branches in the main loop
// (round-5 lesson: branchy unrolled loops defeat LDS latency pipelining) and
// NO LDS atomics (128-way same-address RMW serializes: 513k conflicts).
// One sqrt per pair: (dy-dx)^2 = d2x + d2y - 2*sqrt(d2x*d2y); diff-form d2 >= 0
// exactly, so the sqrt argument is >= 0 (no fmax/NaN guard needed).
// Final reduction fused via last-block-done (counter zeroed by memsetAsync).
__global__ __launch_bounds__(256) void drmsd_fused(
    const float* __restrict__ x, const float* __restrict__ y,
    float* __restrict__ partials, unsigned* __restrict__ counter,
    float* __restrict__ out)
{
    __shared__ __align__(16) float xsx[2][Tt], xsy[2][Tt], xsz[2][Tt];
    __shared__ __align__(16) float ysx[2][Tt], ysy[2][Tt], ysz[2][Tt];
    __shared__ __align__(16) float ms[2][Tt];
    __shared__ float red[4];
    __shared__ int   lastFlag;
    __shared__ float sums[256];

    const int b = blockIdx.x;      // batch
    const int p = blockIdx.y;      // triangular pair index 0..35

    // decode p -> (ti, tj), ti <= tj
    int ti = 0, base = 0;
    while (p >= base + (NTILE - ti)) { base += (NTILE - ti); ++ti; }
    const int tj = ti + (p - base);

    const int t = threadIdx.x;

    // ---- stage: threads 0-127 -> i-tile (slot 0), 128-255 -> j-tile (slot 1)
    {
        const int r     = t & (Tt - 1);
        const int which = t >> 7;
        const int tile  = which ? tj : ti;
        const int row   = tile * Tt + r;
        const float* px = x + (size_t)row * (Bp * 3) + (size_t)b * 3;
        const float* py = y + (size_t)row * (Bp * 3) + (size_t)b * 3;
        const float x0 = px[0], x1 = px[1], x2 = px[2];
        const float y0 = py[0], y1 = py[1], y2 = py[2];
        xsx[which][r] = x0; xsy[which][r] = x1; xsz[which][r] = x2;
        ysx[which][r] = y0; ysy[which][r] = y1; ysz[which][r] = y2;
        ms[which][r]  = ((y0 + y1 + y2) != 0.0f) ? 1.0f : 0.0f;
    }
    __syncthreads();

    const int jsl = (t & 7) << 2;    // j col offset within 32-group: 0,4,..,28
    const int rg  = t >> 3;          // 0..31
    const int i0  = rg << 2;         // i-rows i0..i0+3
    const int wv  = t >> 6;          // wave id

    // i-row registers (b128 loads; 8 distinct 16B addrs span 128B = all banks once)
    const float4 v_xx = *(const float4*)&xsx[0][i0];
    const float4 v_xy = *(const float4*)&xsy[0][i0];
    const float4 v_xz = *(const float4*)&xsz[0][i0];
    const float4 v_yx = *(const float4*)&ysx[0][i0];
    const float4 v_yy = *(const float4*)&ysy[0][i0];
    const float4 v_yz = *(const float4*)&ysz[0][i0];
    const float4 v_mi = *(const float4*)&ms[0][i0];
    const float xix[4] = { v_xx.x, v_xx.y, v_xx.z, v_xx.w };
    const float xiy[4] = { v_xy.x, v_xy.y, v_xy.z, v_xy.w };
    const float xiz[4] = { v_xz.x, v_xz.y, v_xz.z, v_xz.w };
    const float yix[4] = { v_yx.x, v_yx.y, v_yx.z, v_yx.w };
    const float yiy[4] = { v_yy.x, v_yy.y, v_yy.z, v_yy.w };
    const float yiz[4] = { v_yz.x, v_yz.y, v_yz.z, v_yz.w };
    const float mir[4] = { v_mi.x, v_mi.y, v_mi.z, v_mi.w };

    v4f acc[4];
#pragma unroll
    for (int r = 0; r < 4; ++r) acc[r] = splat4(0.0f);

    const v4f neg2 = splat4(-2.0f);

#pragma unroll
    for (int jj = 0; jj < 4; ++jj) {
        const int j0 = jj * 32 + jsl;
        const v4f xjx = *(const v4f*)&xsx[1][j0];
        const v4f xjy = *(const v4f*)&xsy[1][j0];
        const v4f xjz = *(const v4f*)&xsz[1][j0];
        const v4f yjx = *(const v4f*)&ysx[1][j0];
        const v4f yjy = *(const v4f*)&ysy[1][j0];
        const v4f yjz = *(const v4f*)&ysz[1][j0];
        const v4f mj  = *(const v4f*)&ms[1][j0];
#pragma unroll
        for (int r = 0; r < 4; ++r) {
            const v4f ax = splat4(xix[r]) - xjx;
            const v4f ay = splat4(xiy[r]) - xjy;
            const v4f az = splat4(xiz[r]) - xjz;
            const v4f d2x = ax * ax + ay * ay + az * az;   // pk_fma chain
            const v4f bx = splat4(yix[r]) - yjx;
            const v4f by = splat4(yiy[r]) - yjy;
            const v4f bz = splat4(yiz[r]) - yjz;
            const v4f d2y = bx * bx + by * by + bz * bz;
            const v4f pr = d2x * d2y;                      // exactly >= 0
            v4f sq;
            sq.x = __builtin_amdgcn_sqrtf(pr.x);
            sq.y = __builtin_amdgcn_sqrtf(pr.y);
            sq.z = __builtin_amdgcn_sqrtf(pr.z);
            sq.w = __builtin_amdgcn_sqrtf(pr.w);
            const v4f u = (d2x + d2y) + neg2 * sq;
            acc[r] = mj * u + acc[r];                      // col mask
        }
    }

    float total = 0.0f;
#pragma unroll
    for (int r = 0; r < 4; ++r)
        total = fmaf(acc[r].x + acc[r].y + acc[r].z + acc[r].w, mir[r], total);

    // ---- block reduction ----
#pragma unroll
    for (int off = 32; off > 0; off >>= 1)
        total += __shfl_down(total, off, 64);
    if ((t & 63) == 0) red[wv] = total;
    __syncthreads();
    if (t == 0) {
        float s = red[0] + red[1] + red[2] + red[3];
        if (ti != tj) s *= 2.0f;   // off-diagonal pair counted for both orders
        partials[(size_t)p * Bp + b] = s;
        __threadfence();           // release: partial visible before signaling
        const unsigned old = atomicAdd(counter, 1u);
        lastFlag = (old == NBLK - 1) ? 1 : 0;   // every block's t0 writes this
    }
    __syncthreads();

    // ---- last block performs the final reduction ----
    if (lastFlag) {
        __threadfence();           // acquire: see all partials
        const int lane = t & 63;
        const int q    = t >> 6;   // wave q handles 9 p's
        float s = 0.0f;
#pragma unroll
        for (int k = 0; k < 9; ++k) {
            const int pidx = q * 9 + k;
            s += partials[(size_t)pidx * Bp + lane];   // coalesced
        }
        sums[t] = s;
        __syncthreads();
        if (t < 64) {
            float v = sums[t] + sums[t + 64] + sums[t + 128] + sums[t + 192];
            float pb = sqrtf(v);
#pragma unroll
            for (int off = 32; off > 0; off >>= 1)
                pb += __shfl_down(pb, off, 64);
            if (t == 0) {
                const double denom = sqrt((double)Lp * (double)Lp / 2.0 - (double)Lp);
                out[0] = (float)((double)pb / denom / (double)Bp);
            }
        }
    }
}

extern "C" void kernel_launch(void* const* d_in, const int* in_sizes, int n_in,
                              void* d_out, int out_size, void* d_ws, size_t ws_size,
                              hipStream_t stream) {
    const float* x = (const float*)d_in[0];
    const float* y = (const float*)d_in[1];
    float* out      = (float*)d_out;
    float* partials = (float*)d_ws;                       // NPAIR*Bp floats = 9216 B
    unsigned* counter = (unsigned*)((char*)d_ws + 9216);  // 4 B

    hipMemsetAsync(counter, 0, sizeof(unsigned), stream);
    dim3 grid(Bp, NPAIR);
    drmsd_fused<<<grid, 256, 0, stream>>>(x, y, partials, counter, out);
}

// Round 7
// 73.685 us; speedup vs baseline: 1.4187x; 1.4060x over previous
//
#include <hip/hip_runtime.h>
#include <math.h>

// Problem constants (match reference)
#define Lp 1024
#define Bp 64
#define Tt 128          // tile rows
#define NTILE 8         // Lp / Tt
#define NPAIR 36        // NTILE*(NTILE+1)/2 triangular tile pairs

typedef float v4f __attribute__((ext_vector_type(4)));
static __device__ __forceinline__ v4f splat4(float s) {
    v4f r; r.x = s; r.y = s; r.z = s; r.w = s; return r;
}

// One block = one (batch, triangular tile-pair), 256 threads.
// Lane map: jsl = (t&7)*4 -> 4 adjacent j columns (ds_read_b128 + pk-f32),
//           rg  = t>>3 in 0..31 -> i-rows [rg*4, rg*4+4).
// 4 rows x 16 cols = 64 pairs/thread. Straight-line inner loop (no branches,
// no LDS atomics). One sqrt per pair: (dy-dx)^2 = d2x + d2y - 2*sqrt(d2x*d2y);
// diff-form d2 is exactly >= 0 so the sqrt argument needs no guard.
// NOTE (round 5/6 lesson): do NOT fuse the final reduction via per-block
// __threadfence + device atomic — on gfx950 the agent-scope release forces an
// L2 writeback per block (non-coherent per-XCD L2s), serializing block
// retirement: main kernel went 20 -> 52 us. Two launches are cheaper.
__global__ __launch_bounds__(256) void drmsd_main(
    const float* __restrict__ x, const float* __restrict__ y,
    float* __restrict__ partials)
{
    __shared__ __align__(16) float xsx[2][Tt], xsy[2][Tt], xsz[2][Tt];
    __shared__ __align__(16) float ysx[2][Tt], ysy[2][Tt], ysz[2][Tt];
    __shared__ __align__(16) float ms[2][Tt];
    __shared__ float red[4];

    const int b = blockIdx.x;      // batch
    const int p = blockIdx.y;      // triangular pair index 0..35

    // decode p -> (ti, tj), ti <= tj
    int ti = 0, base = 0;
    while (p >= base + (NTILE - ti)) { base += (NTILE - ti); ++ti; }
    const int tj = ti + (p - base);

    const int t = threadIdx.x;

    // ---- stage: threads 0-127 -> i-tile (slot 0), 128-255 -> j-tile (slot 1)
    {
        const int r     = t & (Tt - 1);
        const int which = t >> 7;
        const int tile  = which ? tj : ti;
        const int row   = tile * Tt + r;
        const float* px = x + (size_t)row * (Bp * 3) + (size_t)b * 3;
        const float* py = y + (size_t)row * (Bp * 3) + (size_t)b * 3;
        const float x0 = px[0], x1 = px[1], x2 = px[2];
        const float y0 = py[0], y1 = py[1], y2 = py[2];
        xsx[which][r] = x0; xsy[which][r] = x1; xsz[which][r] = x2;
        ysx[which][r] = y0; ysy[which][r] = y1; ysz[which][r] = y2;
        ms[which][r]  = ((y0 + y1 + y2) != 0.0f) ? 1.0f : 0.0f;
    }
    __syncthreads();

    const int jsl = (t & 7) << 2;    // j col offset within 32-group: 0,4,..,28
    const int rg  = t >> 3;          // 0..31
    const int i0  = rg << 2;         // i-rows i0..i0+3
    const int wv  = t >> 6;          // wave id

    // i-row registers (b128 broadcast loads: 8 distinct addrs/wave, conflict-free)
    const float4 v_xx = *(const float4*)&xsx[0][i0];
    const float4 v_xy = *(const float4*)&xsy[0][i0];
    const float4 v_xz = *(const float4*)&xsz[0][i0];
    const float4 v_yx = *(const float4*)&ysx[0][i0];
    const float4 v_yy = *(const float4*)&ysy[0][i0];
    const float4 v_yz = *(const float4*)&ysz[0][i0];
    const float4 v_mi = *(const float4*)&ms[0][i0];
    const float xix[4] = { v_xx.x, v_xx.y, v_xx.z, v_xx.w };
    const float xiy[4] = { v_xy.x, v_xy.y, v_xy.z, v_xy.w };
    const float xiz[4] = { v_xz.x, v_xz.y, v_xz.z, v_xz.w };
    const float yix[4] = { v_yx.x, v_yx.y, v_yx.z, v_yx.w };
    const float yiy[4] = { v_yy.x, v_yy.y, v_yy.z, v_yy.w };
    const float yiz[4] = { v_yz.x, v_yz.y, v_yz.z, v_yz.w };
    const float mir[4] = { v_mi.x, v_mi.y, v_mi.z, v_mi.w };

    v4f acc[4];
#pragma unroll
    for (int r = 0; r < 4; ++r) acc[r] = splat4(0.0f);

    const v4f neg2 = splat4(-2.0f);

#pragma unroll
    for (int jj = 0; jj < 4; ++jj) {
        const int j0 = jj * 32 + jsl;
        const v4f xjx = *(const v4f*)&xsx[1][j0];
        const v4f xjy = *(const v4f*)&xsy[1][j0];
        const v4f xjz = *(const v4f*)&xsz[1][j0];
        const v4f yjx = *(const v4f*)&ysx[1][j0];
        const v4f yjy = *(const v4f*)&ysy[1][j0];
        const v4f yjz = *(const v4f*)&ysz[1][j0];
        const v4f mj  = *(const v4f*)&ms[1][j0];
#pragma unroll
        for (int r = 0; r < 4; ++r) {
            const v4f ax = splat4(xix[r]) - xjx;
            const v4f ay = splat4(xiy[r]) - xjy;
            const v4f az = splat4(xiz[r]) - xjz;
            const v4f d2x = ax * ax + ay * ay + az * az;   // pk_fma chain
            const v4f bx = splat4(yix[r]) - yjx;
            const v4f by = splat4(yiy[r]) - yjy;
            const v4f bz = splat4(yiz[r]) - yjz;
            const v4f d2y = bx * bx + by * by + bz * bz;
            const v4f pr = d2x * d2y;                      // exactly >= 0
            v4f sq;
            sq.x = __builtin_amdgcn_sqrtf(pr.x);
            sq.y = __builtin_amdgcn_sqrtf(pr.y);
            sq.z = __builtin_amdgcn_sqrtf(pr.z);
            sq.w = __builtin_amdgcn_sqrtf(pr.w);
            const v4f u = (d2x + d2y) + neg2 * sq;
            acc[r] = mj * u + acc[r];                      // col mask
        }
    }

    float total = 0.0f;
#pragma unroll
    for (int r = 0; r < 4; ++r)
        total = fmaf(acc[r].x + acc[r].y + acc[r].z + acc[r].w, mir[r], total);

    // ---- block reduction ----
#pragma unroll
    for (int off = 32; off > 0; off >>= 1)
        total += __shfl_down(total, off, 64);
    if ((t & 63) == 0) red[wv] = total;
    __syncthreads();
    if (t == 0) {
        float s = red[0] + red[1] + red[2] + red[3];
        if (ti != tj) s *= 2.0f;   // off-diagonal pair counted for both orders
        partials[(size_t)p * Bp + b] = s;   // [p][b] -> coalesced final reads
    }
}

__global__ __launch_bounds__(256) void drmsd_final(
    const float* __restrict__ partials, float* __restrict__ out)
{
    __shared__ float sums[256];
    const int t    = threadIdx.x;
    const int lane = t & 63;
    const int q    = t >> 6;       // wave q handles 9 p's
    float s = 0.0f;
#pragma unroll
    for (int k = 0; k < 9; ++k) {
        const int pidx = q * 9 + k;
        s += partials[(size_t)pidx * Bp + lane];   // coalesced across lanes
    }
    sums[t] = s;
    __syncthreads();
    if (t < 64) {
        float v = sums[t] + sums[t + 64] + sums[t + 128] + sums[t + 192];
        float pb = sqrtf(v);
#pragma unroll
        for (int off = 32; off > 0; off >>= 1)
            pb += __shfl_down(pb, off, 64);
        if (t == 0) {
            const double denom = sqrt((double)Lp * (double)Lp / 2.0 - (double)Lp);
            out[0] = (float)((double)pb / denom / (double)Bp);
        }
    }
}

extern "C" void kernel_launch(void* const* d_in, const int* in_sizes, int n_in,
                              void* d_out, int out_size, void* d_ws, size_t ws_size,
                              hipStream_t stream) {
    const float* x = (const float*)d_in[0];
    const float* y = (const float*)d_in[1];
    float* out      = (float*)d_out;
    float* partials = (float*)d_ws;   // NPAIR * Bp floats = 9216 B

    dim3 grid(Bp, NPAIR);
    drmsd_main<<<grid, 256, 0, stream>>>(x, y, partials);
    drmsd_final<<<1, 256, 0, stream>>>(partials, out);
}